// Round 5
// baseline (1926.221 us; speedup 1.0000x reference)
//
#include <hip/hip_runtime.h>
#include <math.h>

#define BB 4
#define TT 784
#define GG 28
#define EE 768
#define HDIM 3072
#define NHEAD 12
#define NLAYER 6
#define TTP 832           // padded token stride for vT

typedef short bfrag __attribute__((ext_vector_type(8)));   // 8 bf16 = 4 VGPRs
typedef float ffrag __attribute__((ext_vector_type(4)));   // 4 fp32 acc

__device__ __forceinline__ unsigned short f2b(float f) {
    union { float f; unsigned u; } v; v.f = f;
    unsigned r = v.u + 0x7FFF + ((v.u >> 16) & 1);         // RNE
    return (unsigned short)(r >> 16);
}

#define GLOAD_LDS16(g, l)                                                          \
    __builtin_amdgcn_global_load_lds(                                              \
        (const __attribute__((address_space(1))) void*)(g),                        \
        (__attribute__((address_space(3))) void*)(l), 16, 0, 0)

// ---------------------------------------------------------------- reductions
__device__ __forceinline__ float block_reduce_sum256(float v, volatile float* sb) {
    #pragma unroll
    for (int m = 1; m < 64; m <<= 1) v += __shfl_xor(v, m, 64);
    int wave = threadIdx.x >> 6;
    if ((threadIdx.x & 63) == 0) sb[wave] = v;
    __syncthreads();
    return sb[0] + sb[1] + sb[2] + sb[3];
}

// ---------------------------------------------------------------- fp32 -> bf16 cast
__global__ __launch_bounds__(256) void cast_kernel(const float* __restrict__ s,
                                                   unsigned short* __restrict__ d, int n4) {
    int i = blockIdx.x * 256 + threadIdx.x;
    if (i >= n4) return;
    float4 v = ((const float4*)s)[i];
    ushort4 o;
    o.x = f2b(v.x); o.y = f2b(v.y); o.z = f2b(v.z); o.w = f2b(v.w);
    ((ushort4*)d)[i] = o;
}

// ---------------------------------------------------------------- fused per-layer weight cast
__global__ __launch_bounds__(256) void fused_cast_kernel(const float* __restrict__ iw,
                                                         const float* __restrict__ ow,
                                                         const float* __restrict__ W1,
                                                         const float* __restrict__ W2,
                                                         unsigned short* __restrict__ dq,
                                                         unsigned short* __restrict__ doo,
                                                         unsigned short* __restrict__ d1,
                                                         unsigned short* __restrict__ d2) {
    int i = blockIdx.x * 256 + threadIdx.x;
    const float* s; unsigned short* d; int k;
    if (i < 442368)            { s = iw;  d = dq;  k = i; }
    else if (i < 589824)       { s = ow;  d = doo; k = i - 442368; }
    else if (i < 1179648)      { s = W1;  d = d1;  k = i - 589824; }
    else if (i < 1769472)      { s = W2;  d = d2;  k = i - 1179648; }
    else return;
    float4 v = ((const float4*)s)[k];
    ushort4 o;
    o.x = f2b(v.x); o.y = f2b(v.y); o.z = f2b(v.z); o.w = f2b(v.w);
    ((ushort4*)d)[k] = o;
}

// ---------------------------------------------------------------- patchify -> bf16
__global__ __launch_bounds__(256) void patchify_kernel(const float* __restrict__ x,
                                                       unsigned short* __restrict__ P) {
    int idx = blockIdx.x * blockDim.x + threadIdx.x;
    const int total = BB * TT * EE;
    if (idx >= total) return;
    int k = idx % EE;
    int t = (idx / EE) % TT;
    int b = idx / (EE * TT);
    int c = k >> 8;
    int rem = k & 255;
    int p1 = rem >> 4;
    int p2 = rem & 15;
    int g1 = t / GG, g2 = t % GG;
    int hh = g1 * 16 + p1, ww = g2 * 16 + p2;
    P[idx] = f2b(x[((b * 448 + hh) * 448 + ww) * 3 + c]);
}

// ---------------------------------------------------------------- pos prefill
__global__ __launch_bounds__(256) void posfill_kernel(float* __restrict__ h,
                                                      const float* __restrict__ pos) {
    int idx = blockIdx.x * blockDim.x + threadIdx.x;
    const int total = BB * TT * EE;
    if (idx >= total) return;
    h[idx] = pos[idx % (TT * EE)];
}

// ---------------------------------------------------------------- layernorm
__global__ __launch_bounds__(256) void ln_kernel(const float* __restrict__ X,
                                                 const float* __restrict__ g,
                                                 const float* __restrict__ bt,
                                                 unsigned short* __restrict__ Yb,
                                                 float* Yf) {
    __shared__ float sb1[4];
    __shared__ float sb2[4];
    int row = blockIdx.x;
    int tid = threadIdx.x;
    const float* x = X + (size_t)row * EE;
    float v0 = x[tid], v1 = x[tid + 256], v2 = x[tid + 512];
    float s = block_reduce_sum256(v0 + v1 + v2, sb1);
    float mean = s * (1.0f / 768.0f);
    float d0 = v0 - mean, d1 = v1 - mean, d2 = v2 - mean;
    __syncthreads();
    float ss = block_reduce_sum256(d0 * d0 + d1 * d1 + d2 * d2, sb2);
    float rstd = rsqrtf(ss * (1.0f / 768.0f) + 1e-5f);
    float y0 = d0 * rstd * g[tid]       + bt[tid];
    float y1 = d1 * rstd * g[tid + 256] + bt[tid + 256];
    float y2 = d2 * rstd * g[tid + 512] + bt[tid + 512];
    unsigned short* yb = Yb + (size_t)row * EE;
    yb[tid] = f2b(y0); yb[tid + 256] = f2b(y1); yb[tid + 512] = f2b(y2);
    if (Yf) {
        float* yf = Yf + (size_t)row * EE;
        yf[tid] = y0; yf[tid + 256] = y1; yf[tid + 512] = y2;
    }
}

// ---------------------------------------------------------------- bf16 MFMA GEMM (generic)
__global__ __launch_bounds__(256) void gemm_bf16(const unsigned short* __restrict__ A,
                                                 const unsigned short* __restrict__ W,
                                                 const float* __restrict__ bias,
                                                 const float* R, float* C,
                                                 unsigned short* Cb,
                                                 int M, int N, int K, int act) {
    __shared__ unsigned short As[128 * 32];
    __shared__ unsigned short Ws[128 * 32];
    int tid = threadIdx.x;
    int wave = tid >> 6, lane = tid & 63;
    int m0 = blockIdx.y << 7, n0 = blockIdx.x << 7;
    int mh = (wave & 1) << 6, nh = (wave >> 1) << 6;

    int cl = lane & 15, qd = lane >> 4;
    int sr = lane >> 2;
    int sc = (lane & 3) << 3;

    const unsigned short* Ap[2];
    const unsigned short* Wp[2];
    unsigned short* lA[2];
    unsigned short* lW[2];
    #pragma unroll
    for (int i = 0; i < 2; i++) {
        int ar = m0 + (wave << 5) + (i << 4) + sr;
        if (ar > M - 1) ar = M - 1;
        Ap[i] = A + (size_t)ar * K + sc;
        int wr = n0 + (wave << 5) + (i << 4) + sr;
        Wp[i] = W + (size_t)wr * K + sc;
        lA[i] = &As[((wave << 5) + (i << 4)) << 5];
        lW[i] = &Ws[((wave << 5) + (i << 4)) << 5];
    }

    ffrag acc[4][4] = {};

    for (int k0 = 0; k0 < K; k0 += 32) {
        __syncthreads();
        GLOAD_LDS16(Ap[0] + k0, lA[0]);
        GLOAD_LDS16(Ap[1] + k0, lA[1]);
        GLOAD_LDS16(Wp[0] + k0, lW[0]);
        GLOAD_LDS16(Wp[1] + k0, lW[1]);
        __syncthreads();

        bfrag af[4], bfr[4];
        #pragma unroll
        for (int i = 0; i < 4; i++)
            af[i] = *(const bfrag*)&As[(((mh + (i << 4) + cl)) << 5) + (qd << 3)];
        #pragma unroll
        for (int j = 0; j < 4; j++)
            bfr[j] = *(const bfrag*)&Ws[(((nh + (j << 4) + cl)) << 5) + (qd << 3)];
        #pragma unroll
        for (int i = 0; i < 4; i++)
            #pragma unroll
            for (int j = 0; j < 4; j++)
                acc[i][j] = __builtin_amdgcn_mfma_f32_16x16x32_bf16(af[i], bfr[j], acc[i][j], 0, 0, 0);
    }

    #pragma unroll
    for (int j = 0; j < 4; j++) {
        int col = n0 + nh + (j << 4) + cl;
        float bv = bias[col];
        #pragma unroll
        for (int i = 0; i < 4; i++) {
            int row0 = m0 + mh + (i << 4) + (qd << 2);
            #pragma unroll
            for (int r = 0; r < 4; r++) {
                int row = row0 + r;
                if (row < M) {
                    float v = acc[i][j][r] + bv;
                    if (R) v += R[(size_t)row * N + col];
                    if (act) v = 0.5f * v * (1.0f + erff(v * 0.70710678118654752f));
                    if (C)  C[(size_t)row * N + col] = v;
                    if (Cb) Cb[(size_t)row * N + col] = f2b(v);
                }
            }
        }
    }
}

// ---------------------------------------------------------------- QKV GEMM: writes Q,K row-major + V transposed
// A [M,768] bf16, W [2304,768] bf16. Q/K: [M,768] bf16. vT: [(b*12+h)*64+d][TTP] bf16.
__global__ __launch_bounds__(256) void gemm_qkv(const unsigned short* __restrict__ A,
                                                const unsigned short* __restrict__ W,
                                                const float* __restrict__ bias,
                                                unsigned short* __restrict__ Q,
                                                unsigned short* __restrict__ Kd,
                                                unsigned short* __restrict__ vT,
                                                int M, int N, int K) {
    __shared__ unsigned short As[128 * 32];
    __shared__ unsigned short Ws[128 * 32];
    int tid = threadIdx.x;
    int wave = tid >> 6, lane = tid & 63;
    int m0 = blockIdx.y << 7, n0 = blockIdx.x << 7;
    int mh = (wave & 1) << 6, nh = (wave >> 1) << 6;

    int cl = lane & 15, qd = lane >> 4;
    int sr = lane >> 2;
    int sc = (lane & 3) << 3;

    const unsigned short* Ap[2];
    const unsigned short* Wp[2];
    unsigned short* lA[2];
    unsigned short* lW[2];
    #pragma unroll
    for (int i = 0; i < 2; i++) {
        int ar = m0 + (wave << 5) + (i << 4) + sr;
        if (ar > M - 1) ar = M - 1;
        Ap[i] = A + (size_t)ar * K + sc;
        int wr = n0 + (wave << 5) + (i << 4) + sr;
        Wp[i] = W + (size_t)wr * K + sc;
        lA[i] = &As[((wave << 5) + (i << 4)) << 5];
        lW[i] = &Ws[((wave << 5) + (i << 4)) << 5];
    }

    ffrag acc[4][4] = {};

    for (int k0 = 0; k0 < K; k0 += 32) {
        __syncthreads();
        GLOAD_LDS16(Ap[0] + k0, lA[0]);
        GLOAD_LDS16(Ap[1] + k0, lA[1]);
        GLOAD_LDS16(Wp[0] + k0, lW[0]);
        GLOAD_LDS16(Wp[1] + k0, lW[1]);
        __syncthreads();

        bfrag af[4], bfr[4];
        #pragma unroll
        for (int i = 0; i < 4; i++)
            af[i] = *(const bfrag*)&As[(((mh + (i << 4) + cl)) << 5) + (qd << 3)];
        #pragma unroll
        for (int j = 0; j < 4; j++)
            bfr[j] = *(const bfrag*)&Ws[(((nh + (j << 4) + cl)) << 5) + (qd << 3)];
        #pragma unroll
        for (int i = 0; i < 4; i++)
            #pragma unroll
            for (int j = 0; j < 4; j++)
                acc[i][j] = __builtin_amdgcn_mfma_f32_16x16x32_bf16(af[i], bfr[j], acc[i][j], 0, 0, 0);
    }

    int nb = n0 + nh;                         // 64-aligned col base for this wave
    if (nb < 1536) {
        // Q or K, row-major
        unsigned short* dst = (nb < 768) ? Q : Kd;
        int cb = (nb < 768) ? 0 : 768;
        #pragma unroll
        for (int j = 0; j < 4; j++) {
            int col = nb + (j << 4) + cl;
            float bv = bias[col];
            #pragma unroll
            for (int i = 0; i < 4; i++) {
                int row0 = m0 + mh + (i << 4) + (qd << 2);
                #pragma unroll
                for (int r = 0; r < 4; r++) {
                    int row = row0 + r;
                    if (row < M)
                        dst[(size_t)row * EE + col - cb] = f2b(acc[i][j][r] + bv);
                }
            }
        }
    } else {
        // V transposed: vT[((b*12+hh)*64 + dl)*TTP + t]
        int hh = (nb - 1536) >> 6;            // uniform per wave
        #pragma unroll
        for (int i = 0; i < 4; i++) {
            int row0 = m0 + mh + (i << 4) + (qd << 2);
            #pragma unroll
            for (int r = 0; r < 4; r++) {
                int row = row0 + r;
                if (row < M) {
                    int b = row / TT;
                    int t = row - b * TT;
                    size_t vbase = ((size_t)(b * NHEAD + hh) * 64) * TTP + t;
                    #pragma unroll
                    for (int j = 0; j < 4; j++) {
                        int col = nb + (j << 4) + cl;
                        vT[vbase + (size_t)((j << 4) + cl) * TTP] =
                            f2b(acc[i][j][r] + bias[col]);
                    }
                }
            }
        }
    }
}

// ---------------------------------------------------------------- split-K bf16 MFMA GEMM (atomic fp32)
__global__ __launch_bounds__(256) void gemm_bf16_sk(const unsigned short* __restrict__ A,
                                                    const unsigned short* __restrict__ W,
                                                    const float* __restrict__ bias,
                                                    float* C,
                                                    int M, int N, int K, int KC) {
    __shared__ unsigned short As[128 * 32];
    __shared__ unsigned short Ws[128 * 32];
    int tid = threadIdx.x;
    int wave = tid >> 6, lane = tid & 63;
    int m0 = blockIdx.y << 7, n0 = blockIdx.x << 7;
    int mh = (wave & 1) << 6, nh = (wave >> 1) << 6;
    int z = blockIdx.z;
    int kbeg = z * KC;
    int kend = kbeg + KC > K ? K : kbeg + KC;

    int cl = lane & 15, qd = lane >> 4;
    int sr = lane >> 2;
    int sc = (lane & 3) << 3;

    const unsigned short* Ap[2];
    const unsigned short* Wp[2];
    unsigned short* lA[2];
    unsigned short* lW[2];
    #pragma unroll
    for (int i = 0; i < 2; i++) {
        int ar = m0 + (wave << 5) + (i << 4) + sr;
        if (ar > M - 1) ar = M - 1;
        Ap[i] = A + (size_t)ar * K + sc;
        int wr = n0 + (wave << 5) + (i << 4) + sr;
        Wp[i] = W + (size_t)wr * K + sc;
        lA[i] = &As[((wave << 5) + (i << 4)) << 5];
        lW[i] = &Ws[((wave << 5) + (i << 4)) << 5];
    }

    ffrag acc[4][4] = {};

    for (int k0 = kbeg; k0 < kend; k0 += 32) {
        __syncthreads();
        GLOAD_LDS16(Ap[0] + k0, lA[0]);
        GLOAD_LDS16(Ap[1] + k0, lA[1]);
        GLOAD_LDS16(Wp[0] + k0, lW[0]);
        GLOAD_LDS16(Wp[1] + k0, lW[1]);
        __syncthreads();

        bfrag af[4], bfr[4];
        #pragma unroll
        for (int i = 0; i < 4; i++)
            af[i] = *(const bfrag*)&As[(((mh + (i << 4) + cl)) << 5) + (qd << 3)];
        #pragma unroll
        for (int j = 0; j < 4; j++)
            bfr[j] = *(const bfrag*)&Ws[(((nh + (j << 4) + cl)) << 5) + (qd << 3)];
        #pragma unroll
        for (int i = 0; i < 4; i++)
            #pragma unroll
            for (int j = 0; j < 4; j++)
                acc[i][j] = __builtin_amdgcn_mfma_f32_16x16x32_bf16(af[i], bfr[j], acc[i][j], 0, 0, 0);
    }

    #pragma unroll
    for (int j = 0; j < 4; j++) {
        int col = n0 + nh + (j << 4) + cl;
        float bv = (z == 0) ? bias[col] : 0.0f;
        #pragma unroll
        for (int i = 0; i < 4; i++) {
            int row0 = m0 + mh + (i << 4) + (qd << 2);
            #pragma unroll
            for (int r = 0; r < 4; r++) {
                int row = row0 + r;
                if (row < M)
                    unsafeAtomicAdd(&C[(size_t)row * N + col], acc[i][j][r] + bv);
            }
        }
    }
}

// ---------------------------------------------------------------- MFMA flash attention v3
// Q,K: [B*T, 768] bf16; vT: [(b*12+h)*64+d][TTP] bf16; O: [B*T, 768] bf16.
// grid (7 q-blocks of 128, B*NH); block 256 = 4 waves, each wave 32 q-rows.
#define LP 72     // LDS row pad (elements)
#define SCL2 0.18033688011112042f   // 0.125 * log2(e)
__global__ __launch_bounds__(256) void attn_kernel(const unsigned short* __restrict__ Qg,
                                                   const unsigned short* __restrict__ Kg,
                                                   const unsigned short* __restrict__ vT,
                                                   unsigned short* __restrict__ O) {
    __shared__ unsigned short Ks[64 * LP];     // [k'][d]
    __shared__ unsigned short Vt[64 * LP];     // [d][k']
    __shared__ unsigned short Pb[128 * LP];    // [q_local][k'], wave-private rows
    int tid = threadIdx.x;
    int wave = tid >> 6, lane = tid & 63;
    int cl = lane & 15, qd = lane >> 4;
    int bh = blockIdx.y;
    int b = bh / NHEAD, hh = bh % NHEAD;
    int q0 = blockIdx.x * 128;
    int qw = q0 + wave * 32;

    // Q fragments: 2 sets of 16 q-rows
    bfrag qf[2][2];
    #pragma unroll
    for (int s = 0; s < 2; s++) {
        int qrow = qw + s * 16 + cl;
        if (qrow > TT - 1) qrow = TT - 1;
        const unsigned short* qb = Qg + (size_t)(b * TT + qrow) * EE + hh * 64;
        qf[s][0] = *(const bfrag*)(qb + (qd << 3));
        qf[s][1] = *(const bfrag*)(qb + 32 + (qd << 3));
    }

    ffrag o_acc[2][4] = {};
    float m_run[2][4], l_run[2][4];
    int qg_[2][4], qr_[2][4], qc_[2][4];
    #pragma unroll
    for (int s = 0; s < 2; s++)
        #pragma unroll
        for (int r = 0; r < 4; r++) {
            qg_[s][r] = qw + s * 16 + (qd << 2) + r;
            qr_[s][r] = qg_[s][r] / GG;
            qc_[s][r] = qg_[s][r] % GG;
            m_run[s][r] = -1e30f; l_run[s][r] = 0.0f;
        }

    // incremental kr/kc per j (kg = k0 + j*16 + cl)
    int kr[4], kc[4];
    #pragma unroll
    for (int j = 0; j < 4; j++) {
        int kg = j * 16 + cl;
        kr[j] = kg / GG; kc[j] = kg % GG;
    }

    const unsigned short* kbase = Kg + (size_t)b * TT * EE + hh * 64;
    const unsigned short* vbase = vT + (size_t)(b * NHEAD + hh) * 64 * TTP;
    int srow = tid >> 3;            // 0..31
    int scol = (tid & 7) << 3;      // 0..56

    for (int k0 = 0; k0 < 832; k0 += 64) {
        __syncthreads();
        #pragma unroll
        for (int it = 0; it < 2; it++) {
            int row = it * 32 + srow;
            int tok = k0 + row; if (tok > TT - 1) tok = TT - 1;
            *(bfrag*)&Ks[row * LP + scol] =
                *(const bfrag*)(kbase + (size_t)tok * EE + scol);
            *(bfrag*)&Vt[row * LP + scol] =
                *(const bfrag*)(vbase + (size_t)row * TTP + k0 + scol);
        }
        __syncthreads();

        // S = Q K^T
        ffrag sv[2][4];
        #pragma unroll
        for (int j = 0; j < 4; j++) {
            bfrag kf0 = *(const bfrag*)&Ks[(j * 16 + cl) * LP + (qd << 3)];
            bfrag kf1 = *(const bfrag*)&Ks[(j * 16 + cl) * LP + 32 + (qd << 3)];
            #pragma unroll
            for (int s = 0; s < 2; s++) {
                ffrag z = {0.f, 0.f, 0.f, 0.f};
                z = __builtin_amdgcn_mfma_f32_16x16x32_bf16(qf[s][0], kf0, z, 0, 0, 0);
                z = __builtin_amdgcn_mfma_f32_16x16x32_bf16(qf[s][1], kf1, z, 0, 0, 0);
                sv[s][j] = z;
            }
        }

        // mask + online softmax (raw s units; scale folded into exp2)
        #pragma unroll
        for (int s = 0; s < 2; s++) {
            #pragma unroll
            for (int j = 0; j < 4; j++) {
                #pragma unroll
                for (int r = 0; r < 4; r++) {
                    bool masked = (kr[j] > 27) ||
                                  (abs(qr_[s][r] - kr[j]) <= 4 && abs(qc_[s][r] - kc[j]) <= 4);
                    if (masked) sv[s][j][r] = -3.0e38f;
                }
            }
            #pragma unroll
            for (int r = 0; r < 4; r++) {
                float mx = fmaxf(fmaxf(sv[s][0][r], sv[s][1][r]),
                                 fmaxf(sv[s][2][r], sv[s][3][r]));
                mx = fmaxf(mx, __shfl_xor(mx, 1, 64));
                mx = fmaxf(mx, __shfl_xor(mx, 2, 64));
                mx = fmaxf(mx, __shfl_xor(mx, 4, 64));
                mx = fmaxf(mx, __shfl_xor(mx, 8, 64));
                float m_new = fmaxf(m_run[s][r], mx);
                float alpha = exp2f((m_run[s][r] - m_new) * SCL2);
                float rs = 0.f;
                float p0 = exp2f((sv[s][0][r] - m_new) * SCL2);
                float p1 = exp2f((sv[s][1][r] - m_new) * SCL2);
                float p2 = exp2f((sv[s][2][r] - m_new) * SCL2);
                float p3 = exp2f((sv[s][3][r] - m_new) * SCL2);
                rs = (p0 + p1) + (p2 + p3);
                rs += __shfl_xor(rs, 1, 64);
                rs += __shfl_xor(rs, 2, 64);
                rs += __shfl_xor(rs, 4, 64);
                rs += __shfl_xor(rs, 8, 64);
                l_run[s][r] = l_run[s][r] * alpha + rs;
                m_run[s][r] = m_new;
                #pragma unroll
                for (int t = 0; t < 4; t++) o_acc[s][t][r] *= alpha;
                int prow = (wave * 32 + s * 16 + (qd << 2) + r) * LP;
                Pb[prow + 0 * 16 + cl] = f2b(p0);
                Pb[prow + 1 * 16 + cl] = f2b(p1);
                Pb[prow + 2 * 16 + cl] = f2b(p2);
                Pb[prow + 3 * 16 + cl] = f2b(p3);
            }
        }
        // wave-private Pb rows: only need this wave's LDS writes drained
        asm volatile("s_waitcnt lgkmcnt(0)" ::: "memory");

        // O += P @ V
        bfrag pf[2][2];
        #pragma unroll
        for (int s = 0; s < 2; s++) {
            pf[s][0] = *(const bfrag*)&Pb[(wave * 32 + s * 16 + cl) * LP + (qd << 3)];
            pf[s][1] = *(const bfrag*)&Pb[(wave * 32 + s * 16 + cl) * LP + 32 + (qd << 3)];
        }
        #pragma unroll
        for (int t = 0; t < 4; t++) {
            bfrag vf0 = *(const bfrag*)&Vt[(t * 16 + cl) * LP + (qd << 3)];
            bfrag vf1 = *(const bfrag*)&Vt[(t * 16 + cl) * LP + 32 + (qd << 3)];
            #pragma unroll
            for (int s = 0; s < 2; s++) {
                o_acc[s][t] = __builtin_amdgcn_mfma_f32_16x16x32_bf16(pf[s][0], vf0, o_acc[s][t], 0, 0, 0);
                o_acc[s][t] = __builtin_amdgcn_mfma_f32_16x16x32_bf16(pf[s][1], vf1, o_acc[s][t], 0, 0, 0);
            }
        }

        // advance kr/kc by 64 tokens (64 = 2*28 + 8)
        #pragma unroll
        for (int j = 0; j < 4; j++) {
            kc[j] += 8; kr[j] += 2;
            if (kc[j] >= GG) { kc[j] -= GG; kr[j] += 1; }
        }
    }

    #pragma unroll
    for (int s = 0; s < 2; s++)
        #pragma unroll
        for (int r = 0; r < 4; r++) {
            if (qg_[s][r] < TT) {
                float inv = 1.0f / fmaxf(l_run[s][r], 1e-30f);
                #pragma unroll
                for (int t = 0; t < 4; t++)
                    O[(size_t)(b * TT + qg_[s][r]) * EE + hh * 64 + t * 16 + cl] =
                        f2b(o_acc[s][t][r] * inv);
            }
        }
}

// ---------------------------------------------------------------- head
__global__ __launch_bounds__(256) void head_kernel(const float* __restrict__ Y,
                                                   const float* __restrict__ hw,
                                                   const float* __restrict__ hb,
                                                   const float* __restrict__ mean_,
                                                   const float* __restrict__ std_,
                                                   float* __restrict__ out) {
    __shared__ float sb[4];
    int row = blockIdx.x;
    int tid = threadIdx.x;
    const float* y = Y + (size_t)row * EE;
    float v = y[tid] * hw[tid] + y[tid + 256] * hw[tid + 256] + y[tid + 512] * hw[tid + 512];
    v = block_reduce_sum256(v, sb);
    if (tid == 0) {
        float logit = v + hb[0];
        float z = logit * std_[0] + mean_[0];
        float f = expf(z * 2.302585092994046f) - 1e-8f;
        f = fminf(fmaxf(f, 1e-15f), 1.0f);
        out[4 + row] = f;
    }
}

__global__ __launch_bounds__(256) void flux_sum_kernel(float* __restrict__ out) {
    __shared__ float sb[4];
    int b = blockIdx.x;
    int tid = threadIdx.x;
    const float* pf = out + 4 + (size_t)b * TT;
    float v = pf[tid] + pf[tid + 256] + pf[tid + 512];
    if (tid < TT - 768) v += pf[tid + 768];
    v = block_reduce_sum256(v, sb);
    if (tid == 0) out[b] = fmaxf(v, 1e-15f);
}

// ---------------------------------------------------------------- host
extern "C" void kernel_launch(void* const* d_in, const int* in_sizes, int n_in,
                              void* d_out, int out_size, void* d_ws, size_t ws_size,
                              hipStream_t stream) {
    const float* x        = (const float*)d_in[0];
    const float* sxr_mean = (const float*)d_in[1];
    const float* sxr_std  = (const float*)d_in[2];
    const float* input_w  = (const float*)d_in[3];
    const float* input_b  = (const float*)d_in[4];
    const float* pos_emb  = (const float*)d_in[5];
    const float* ln1_w    = (const float*)d_in[6];
    const float* ln1_b    = (const float*)d_in[7];
    const float* in_w     = (const float*)d_in[8];
    const float* in_b     = (const float*)d_in[9];
    const float* out_w    = (const float*)d_in[10];
    const float* out_b    = (const float*)d_in[11];
    const float* ln2_w    = (const float*)d_in[12];
    const float* ln2_b    = (const float*)d_in[13];
    const float* w1       = (const float*)d_in[14];
    const float* b1       = (const float*)d_in[15];
    const float* w2       = (const float*)d_in[16];
    const float* b2       = (const float*)d_in[17];
    const float* head_ln_w = (const float*)d_in[18];
    const float* head_ln_b = (const float*)d_in[19];
    const float* head_w   = (const float*)d_in[20];
    const float* head_b   = (const float*)d_in[21];
    float* out = (float*)d_out;

    const size_t NROW = (size_t)BB * TT;               // 3136
    const size_t NE   = NROW * EE;

    float* h   = (float*)d_ws;                         // [3136,768] f32
    float* y32 = h + NE;                               // [3136,768] f32 (head only)
    unsigned short* q_b   = (unsigned short*)(y32 + NE);   // [3136,768] bf16
    unsigned short* k_b   = q_b + NE;                      // [3136,768] bf16
    unsigned short* vT_b  = k_b + NE;                      // [48*64, 832] bf16
    unsigned short* y_b   = vT_b + (size_t)BB * NHEAD * 64 * TTP;
    unsigned short* o_b   = y_b + NE;
    unsigned short* mlp_b = o_b + NE;                  // [3136,3072] bf16
    unsigned short* wq_b  = mlp_b + NROW * HDIM;
    unsigned short* wo_b  = wq_b + (size_t)3 * EE * EE;
    unsigned short* w1_b  = wo_b + (size_t)EE * EE;
    unsigned short* w2_b  = w1_b + (size_t)HDIM * EE;

    const int tot = BB * TT * EE;
    const int GY = (int)((NROW + 127) / 128);          // 25

    patchify_kernel<<<(tot + 255) / 256, 256, 0, stream>>>(x, mlp_b);
    cast_kernel<<<(EE * EE / 4 + 255) / 256, 256, 0, stream>>>(input_w, wo_b, EE * EE / 4);
    posfill_kernel<<<(tot + 255) / 256, 256, 0, stream>>>(h, pos_emb);
    gemm_bf16_sk<<<dim3(EE / 128, GY, 2), 256, 0, stream>>>(
        mlp_b, wo_b, input_b, h, (int)NROW, EE, EE, 384);

    for (int l = 0; l < NLAYER; l++) {
        fused_cast_kernel<<<6912, 256, 0, stream>>>(
            in_w + (size_t)l * 3 * EE * EE, out_w + (size_t)l * EE * EE,
            w1 + (size_t)l * HDIM * EE, w2 + (size_t)l * EE * HDIM,
            wq_b, wo_b, w1_b, w2_b);

        ln_kernel<<<(int)NROW, 256, 0, stream>>>(h, ln1_w + l * EE, ln1_b + l * EE, y_b, nullptr);
        gemm_qkv<<<dim3(3 * EE / 128, GY), 256, 0, stream>>>(
            y_b, wq_b, in_b + (size_t)l * 3 * EE, q_b, k_b, vT_b,
            (int)NROW, 3 * EE, EE);
        attn_kernel<<<dim3(7, BB * NHEAD), 256, 0, stream>>>(q_b, k_b, vT_b, o_b);
        gemm_bf16_sk<<<dim3(EE / 128, GY, 2), 256, 0, stream>>>(
            o_b, wo_b, out_b + (size_t)l * EE, h, (int)NROW, EE, EE, 384);
        ln_kernel<<<(int)NROW, 256, 0, stream>>>(h, ln2_w + l * EE, ln2_b + l * EE, y_b, nullptr);
        gemm_bf16<<<dim3(HDIM / 128, GY), 256, 0, stream>>>(
            y_b, w1_b, b1 + (size_t)l * HDIM, nullptr, nullptr, mlp_b,
            (int)NROW, HDIM, EE, 1);
        gemm_bf16_sk<<<dim3(EE / 128, GY, 4), 256, 0, stream>>>(
            mlp_b, w2_b, b2 + (size_t)l * EE, h, (int)NROW, EE, HDIM, 768);
    }

    ln_kernel<<<(int)NROW, 256, 0, stream>>>(h, head_ln_w, head_ln_b, y_b, y32);
    head_kernel<<<(int)NROW, 256, 0, stream>>>(y32, head_w, head_b, sxr_mean, sxr_std, out);
    flux_sum_kernel<<<BB, 256, 0, stream>>>(out);
}

// Round 6
// 1738.565 us; speedup vs baseline: 1.1079x; 1.1079x over previous
//
#include <hip/hip_runtime.h>
#include <math.h>

#define BB 4
#define TT 784
#define GG 28
#define EE 768
#define HDIM 3072
#define NHEAD 12
#define NLAYER 6
#define TTP 832           // padded token stride for vT

typedef short bfrag __attribute__((ext_vector_type(8)));   // 8 bf16 = 4 VGPRs
typedef float ffrag __attribute__((ext_vector_type(4)));   // 4 fp32 acc

__device__ __forceinline__ unsigned short f2b(float f) {
    union { float f; unsigned u; } v; v.f = f;
    unsigned r = v.u + 0x7FFF + ((v.u >> 16) & 1);         // RNE
    return (unsigned short)(r >> 16);
}

#define GLOAD_LDS16(g, l)                                                          \
    __builtin_amdgcn_global_load_lds(                                              \
        (const __attribute__((address_space(1))) void*)(g),                        \
        (__attribute__((address_space(3))) void*)(l), 16, 0, 0)

// ---------------------------------------------------------------- reductions
__device__ __forceinline__ float block_reduce_sum256(float v, volatile float* sb) {
    #pragma unroll
    for (int m = 1; m < 64; m <<= 1) v += __shfl_xor(v, m, 64);
    int wave = threadIdx.x >> 6;
    if ((threadIdx.x & 63) == 0) sb[wave] = v;
    __syncthreads();
    return sb[0] + sb[1] + sb[2] + sb[3];
}

// ---------------------------------------------------------------- fp32 -> bf16 cast
__global__ __launch_bounds__(256) void cast_kernel(const float* __restrict__ s,
                                                   unsigned short* __restrict__ d, int n4) {
    int i = blockIdx.x * 256 + threadIdx.x;
    if (i >= n4) return;
    float4 v = ((const float4*)s)[i];
    ushort4 o;
    o.x = f2b(v.x); o.y = f2b(v.y); o.z = f2b(v.z); o.w = f2b(v.w);
    ((ushort4*)d)[i] = o;
}

// ---------------------------------------------------------------- fused per-layer weight cast
__global__ __launch_bounds__(256) void fused_cast_kernel(const float* __restrict__ iw,
                                                         const float* __restrict__ ow,
                                                         const float* __restrict__ W1,
                                                         const float* __restrict__ W2,
                                                         unsigned short* __restrict__ dq,
                                                         unsigned short* __restrict__ doo,
                                                         unsigned short* __restrict__ d1,
                                                         unsigned short* __restrict__ d2) {
    int i = blockIdx.x * 256 + threadIdx.x;
    const float* s; unsigned short* d; int k;
    if (i < 442368)            { s = iw;  d = dq;  k = i; }
    else if (i < 589824)       { s = ow;  d = doo; k = i - 442368; }
    else if (i < 1179648)      { s = W1;  d = d1;  k = i - 589824; }
    else if (i < 1769472)      { s = W2;  d = d2;  k = i - 1179648; }
    else return;
    float4 v = ((const float4*)s)[k];
    ushort4 o;
    o.x = f2b(v.x); o.y = f2b(v.y); o.z = f2b(v.z); o.w = f2b(v.w);
    ((ushort4*)d)[k] = o;
}

// ---------------------------------------------------------------- patchify -> bf16
__global__ __launch_bounds__(256) void patchify_kernel(const float* __restrict__ x,
                                                       unsigned short* __restrict__ P) {
    int idx = blockIdx.x * blockDim.x + threadIdx.x;
    const int total = BB * TT * EE;
    if (idx >= total) return;
    int k = idx % EE;
    int t = (idx / EE) % TT;
    int b = idx / (EE * TT);
    int c = k >> 8;
    int rem = k & 255;
    int p1 = rem >> 4;
    int p2 = rem & 15;
    int g1 = t / GG, g2 = t % GG;
    int hh = g1 * 16 + p1, ww = g2 * 16 + p2;
    P[idx] = f2b(x[((b * 448 + hh) * 448 + ww) * 3 + c]);
}

// ---------------------------------------------------------------- pos prefill
__global__ __launch_bounds__(256) void posfill_kernel(float* __restrict__ h,
                                                      const float* __restrict__ pos) {
    int idx = blockIdx.x * blockDim.x + threadIdx.x;
    const int total = BB * TT * EE;
    if (idx >= total) return;
    h[idx] = pos[idx % (TT * EE)];
}

// ---------------------------------------------------------------- layernorm
__global__ __launch_bounds__(256) void ln_kernel(const float* __restrict__ X,
                                                 const float* __restrict__ g,
                                                 const float* __restrict__ bt,
                                                 unsigned short* __restrict__ Yb,
                                                 float* Yf) {
    __shared__ float sb1[4];
    __shared__ float sb2[4];
    int row = blockIdx.x;
    int tid = threadIdx.x;
    const float* x = X + (size_t)row * EE;
    float v0 = x[tid], v1 = x[tid + 256], v2 = x[tid + 512];
    float s = block_reduce_sum256(v0 + v1 + v2, sb1);
    float mean = s * (1.0f / 768.0f);
    float d0 = v0 - mean, d1 = v1 - mean, d2 = v2 - mean;
    __syncthreads();
    float ss = block_reduce_sum256(d0 * d0 + d1 * d1 + d2 * d2, sb2);
    float rstd = rsqrtf(ss * (1.0f / 768.0f) + 1e-5f);
    float y0 = d0 * rstd * g[tid]       + bt[tid];
    float y1 = d1 * rstd * g[tid + 256] + bt[tid + 256];
    float y2 = d2 * rstd * g[tid + 512] + bt[tid + 512];
    unsigned short* yb = Yb + (size_t)row * EE;
    yb[tid] = f2b(y0); yb[tid + 256] = f2b(y1); yb[tid + 512] = f2b(y2);
    if (Yf) {
        float* yf = Yf + (size_t)row * EE;
        yf[tid] = y0; yf[tid + 256] = y1; yf[tid + 512] = y2;
    }
}

// ---------------------------------------------------------------- bf16 MFMA GEMM (generic)
__global__ __launch_bounds__(256) void gemm_bf16(const unsigned short* __restrict__ A,
                                                 const unsigned short* __restrict__ W,
                                                 const float* __restrict__ bias,
                                                 const float* R, float* C,
                                                 unsigned short* Cb,
                                                 int M, int N, int K, int act) {
    __shared__ unsigned short As[128 * 32];
    __shared__ unsigned short Ws[128 * 32];
    int tid = threadIdx.x;
    int wave = tid >> 6, lane = tid & 63;
    int m0 = blockIdx.y << 7, n0 = blockIdx.x << 7;
    int mh = (wave & 1) << 6, nh = (wave >> 1) << 6;

    int cl = lane & 15, qd = lane >> 4;
    int sr = lane >> 2;
    int sc = (lane & 3) << 3;

    const unsigned short* Ap[2];
    const unsigned short* Wp[2];
    unsigned short* lA[2];
    unsigned short* lW[2];
    #pragma unroll
    for (int i = 0; i < 2; i++) {
        int ar = m0 + (wave << 5) + (i << 4) + sr;
        if (ar > M - 1) ar = M - 1;
        Ap[i] = A + (size_t)ar * K + sc;
        int wr = n0 + (wave << 5) + (i << 4) + sr;
        Wp[i] = W + (size_t)wr * K + sc;
        lA[i] = &As[((wave << 5) + (i << 4)) << 5];
        lW[i] = &Ws[((wave << 5) + (i << 4)) << 5];
    }

    ffrag acc[4][4] = {};

    for (int k0 = 0; k0 < K; k0 += 32) {
        __syncthreads();
        GLOAD_LDS16(Ap[0] + k0, lA[0]);
        GLOAD_LDS16(Ap[1] + k0, lA[1]);
        GLOAD_LDS16(Wp[0] + k0, lW[0]);
        GLOAD_LDS16(Wp[1] + k0, lW[1]);
        __syncthreads();

        bfrag af[4], bfr[4];
        #pragma unroll
        for (int i = 0; i < 4; i++)
            af[i] = *(const bfrag*)&As[(((mh + (i << 4) + cl)) << 5) + (qd << 3)];
        #pragma unroll
        for (int j = 0; j < 4; j++)
            bfr[j] = *(const bfrag*)&Ws[(((nh + (j << 4) + cl)) << 5) + (qd << 3)];
        #pragma unroll
        for (int i = 0; i < 4; i++)
            #pragma unroll
            for (int j = 0; j < 4; j++)
                acc[i][j] = __builtin_amdgcn_mfma_f32_16x16x32_bf16(af[i], bfr[j], acc[i][j], 0, 0, 0);
    }

    #pragma unroll
    for (int j = 0; j < 4; j++) {
        int col = n0 + nh + (j << 4) + cl;
        float bv = bias[col];
        #pragma unroll
        for (int i = 0; i < 4; i++) {
            int row0 = m0 + mh + (i << 4) + (qd << 2);
            #pragma unroll
            for (int r = 0; r < 4; r++) {
                int row = row0 + r;
                if (row < M) {
                    float v = acc[i][j][r] + bv;
                    if (R) v += R[(size_t)row * N + col];
                    if (act) v = 0.5f * v * (1.0f + erff(v * 0.70710678118654752f));
                    if (C)  C[(size_t)row * N + col] = v;
                    if (Cb) Cb[(size_t)row * N + col] = f2b(v);
                }
            }
        }
    }
}

// ---------------------------------------------------------------- QKV GEMM: writes Q,K row-major + V transposed
__global__ __launch_bounds__(256) void gemm_qkv(const unsigned short* __restrict__ A,
                                                const unsigned short* __restrict__ W,
                                                const float* __restrict__ bias,
                                                unsigned short* __restrict__ Q,
                                                unsigned short* __restrict__ Kd,
                                                unsigned short* __restrict__ vT,
                                                int M, int N, int K) {
    __shared__ unsigned short As[128 * 32];
    __shared__ unsigned short Ws[128 * 32];
    int tid = threadIdx.x;
    int wave = tid >> 6, lane = tid & 63;
    int m0 = blockIdx.y << 7, n0 = blockIdx.x << 7;
    int mh = (wave & 1) << 6, nh = (wave >> 1) << 6;

    int cl = lane & 15, qd = lane >> 4;
    int sr = lane >> 2;
    int sc = (lane & 3) << 3;

    const unsigned short* Ap[2];
    const unsigned short* Wp[2];
    unsigned short* lA[2];
    unsigned short* lW[2];
    #pragma unroll
    for (int i = 0; i < 2; i++) {
        int ar = m0 + (wave << 5) + (i << 4) + sr;
        if (ar > M - 1) ar = M - 1;
        Ap[i] = A + (size_t)ar * K + sc;
        int wr = n0 + (wave << 5) + (i << 4) + sr;
        Wp[i] = W + (size_t)wr * K + sc;
        lA[i] = &As[((wave << 5) + (i << 4)) << 5];
        lW[i] = &Ws[((wave << 5) + (i << 4)) << 5];
    }

    ffrag acc[4][4] = {};

    for (int k0 = 0; k0 < K; k0 += 32) {
        __syncthreads();
        GLOAD_LDS16(Ap[0] + k0, lA[0]);
        GLOAD_LDS16(Ap[1] + k0, lA[1]);
        GLOAD_LDS16(Wp[0] + k0, lW[0]);
        GLOAD_LDS16(Wp[1] + k0, lW[1]);
        __syncthreads();

        bfrag af[4], bfr[4];
        #pragma unroll
        for (int i = 0; i < 4; i++)
            af[i] = *(const bfrag*)&As[(((mh + (i << 4) + cl)) << 5) + (qd << 3)];
        #pragma unroll
        for (int j = 0; j < 4; j++)
            bfr[j] = *(const bfrag*)&Ws[(((nh + (j << 4) + cl)) << 5) + (qd << 3)];
        #pragma unroll
        for (int i = 0; i < 4; i++)
            #pragma unroll
            for (int j = 0; j < 4; j++)
                acc[i][j] = __builtin_amdgcn_mfma_f32_16x16x32_bf16(af[i], bfr[j], acc[i][j], 0, 0, 0);
    }

    int nb = n0 + nh;                         // 64-aligned col base for this wave
    if (nb < 1536) {
        unsigned short* dst = (nb < 768) ? Q : Kd;
        int cb = (nb < 768) ? 0 : 768;
        #pragma unroll
        for (int j = 0; j < 4; j++) {
            int col = nb + (j << 4) + cl;
            float bv = bias[col];
            #pragma unroll
            for (int i = 0; i < 4; i++) {
                int row0 = m0 + mh + (i << 4) + (qd << 2);
                #pragma unroll
                for (int r = 0; r < 4; r++) {
                    int row = row0 + r;
                    if (row < M)
                        dst[(size_t)row * EE + col - cb] = f2b(acc[i][j][r] + bv);
                }
            }
        }
    } else {
        int hh = (nb - 1536) >> 6;            // uniform per wave
        #pragma unroll
        for (int i = 0; i < 4; i++) {
            int row0 = m0 + mh + (i << 4) + (qd << 2);
            #pragma unroll
            for (int r = 0; r < 4; r++) {
                int row = row0 + r;
                if (row < M) {
                    int b = row / TT;
                    int t = row - b * TT;
                    size_t vbase = ((size_t)(b * NHEAD + hh) * 64) * TTP + t;
                    #pragma unroll
                    for (int j = 0; j < 4; j++) {
                        int col = nb + (j << 4) + cl;
                        vT[vbase + (size_t)((j << 4) + cl) * TTP] =
                            f2b(acc[i][j][r] + bias[col]);
                    }
                }
            }
        }
    }
}

// ---------------------------------------------------------------- split-K bf16 MFMA GEMM (atomic fp32)
__global__ __launch_bounds__(256) void gemm_bf16_sk(const unsigned short* __restrict__ A,
                                                    const unsigned short* __restrict__ W,
                                                    const float* __restrict__ bias,
                                                    float* C,
                                                    int M, int N, int K, int KC) {
    __shared__ unsigned short As[128 * 32];
    __shared__ unsigned short Ws[128 * 32];
    int tid = threadIdx.x;
    int wave = tid >> 6, lane = tid & 63;
    int m0 = blockIdx.y << 7, n0 = blockIdx.x << 7;
    int mh = (wave & 1) << 6, nh = (wave >> 1) << 6;
    int z = blockIdx.z;
    int kbeg = z * KC;
    int kend = kbeg + KC > K ? K : kbeg + KC;

    int cl = lane & 15, qd = lane >> 4;
    int sr = lane >> 2;
    int sc = (lane & 3) << 3;

    const unsigned short* Ap[2];
    const unsigned short* Wp[2];
    unsigned short* lA[2];
    unsigned short* lW[2];
    #pragma unroll
    for (int i = 0; i < 2; i++) {
        int ar = m0 + (wave << 5) + (i << 4) + sr;
        if (ar > M - 1) ar = M - 1;
        Ap[i] = A + (size_t)ar * K + sc;
        int wr = n0 + (wave << 5) + (i << 4) + sr;
        Wp[i] = W + (size_t)wr * K + sc;
        lA[i] = &As[((wave << 5) + (i << 4)) << 5];
        lW[i] = &Ws[((wave << 5) + (i << 4)) << 5];
    }

    ffrag acc[4][4] = {};

    for (int k0 = kbeg; k0 < kend; k0 += 32) {
        __syncthreads();
        GLOAD_LDS16(Ap[0] + k0, lA[0]);
        GLOAD_LDS16(Ap[1] + k0, lA[1]);
        GLOAD_LDS16(Wp[0] + k0, lW[0]);
        GLOAD_LDS16(Wp[1] + k0, lW[1]);
        __syncthreads();

        bfrag af[4], bfr[4];
        #pragma unroll
        for (int i = 0; i < 4; i++)
            af[i] = *(const bfrag*)&As[(((mh + (i << 4) + cl)) << 5) + (qd << 3)];
        #pragma unroll
        for (int j = 0; j < 4; j++)
            bfr[j] = *(const bfrag*)&Ws[(((nh + (j << 4) + cl)) << 5) + (qd << 3)];
        #pragma unroll
        for (int i = 0; i < 4; i++)
            #pragma unroll
            for (int j = 0; j < 4; j++)
                acc[i][j] = __builtin_amdgcn_mfma_f32_16x16x32_bf16(af[i], bfr[j], acc[i][j], 0, 0, 0);
    }

    #pragma unroll
    for (int j = 0; j < 4; j++) {
        int col = n0 + nh + (j << 4) + cl;
        float bv = (z == 0) ? bias[col] : 0.0f;
        #pragma unroll
        for (int i = 0; i < 4; i++) {
            int row0 = m0 + mh + (i << 4) + (qd << 2);
            #pragma unroll
            for (int r = 0; r < 4; r++) {
                int row = row0 + r;
                if (row < M)
                    unsafeAtomicAdd(&C[(size_t)row * N + col], acc[i][j][r] + bv);
            }
        }
    }
}

// ---------------------------------------------------------------- MFMA flash attention v4
// Q,K: [B*T, 768] bf16; vT: [(b*12+h)*64+d][TTP] bf16; O: [B*T, 768] bf16.
// grid (13 q-tiles of 64, B*NH); block 256 = 4 waves, each wave 16 q-rows.
#define LP 72
#define SCL2 0.18033688011112042f   // 0.125 * log2(e)
__global__ __launch_bounds__(256) void attn_kernel(const unsigned short* __restrict__ Qg,
                                                   const unsigned short* __restrict__ Kg,
                                                   const unsigned short* __restrict__ vT,
                                                   unsigned short* __restrict__ O) {
    __shared__ unsigned short Ks[64 * LP];     // [k'][d]
    __shared__ unsigned short Vt[64 * LP];     // [d][k']
    __shared__ unsigned short Pb[64 * LP];     // [q_local][k'], wave-private rows
    int tid = threadIdx.x;
    int wave = tid >> 6, lane = tid & 63;
    int cl = lane & 15, qd = lane >> 4;
    int bh = blockIdx.y;
    int b = bh / NHEAD, hh = bh % NHEAD;
    int q0 = blockIdx.x * 64;
    int qw = q0 + wave * 16;

    int qrow = qw + cl;
    if (qrow > TT - 1) qrow = TT - 1;
    const unsigned short* qb = Qg + (size_t)(b * TT + qrow) * EE + hh * 64;
    bfrag qf0 = *(const bfrag*)(qb + (qd << 3));
    bfrag qf1 = *(const bfrag*)(qb + 32 + (qd << 3));

    ffrag o_acc[4] = {};
    float m_run[4], l_run[4];
    int qg_[4], qr_[4], qc_[4];
    #pragma unroll
    for (int r = 0; r < 4; r++) {
        qg_[r] = qw + (qd << 2) + r;
        qr_[r] = qg_[r] / GG;
        qc_[r] = qg_[r] % GG;
        m_run[r] = -1e30f; l_run[r] = 0.0f;
    }

    int kr[4], kc[4];
    #pragma unroll
    for (int j = 0; j < 4; j++) {
        int kg = j * 16 + cl;
        kr[j] = kg / GG; kc[j] = kg % GG;
    }

    const unsigned short* kbase = Kg + (size_t)b * TT * EE + hh * 64;
    const unsigned short* vbase = vT + (size_t)(b * NHEAD + hh) * 64 * TTP;
    int srow = tid >> 3;            // 0..31
    int scol = (tid & 7) << 3;      // 0..56

    for (int k0 = 0; k0 < 832; k0 += 64) {
        __syncthreads();
        #pragma unroll
        for (int it = 0; it < 2; it++) {
            int row = it * 32 + srow;
            int tok = k0 + row; if (tok > TT - 1) tok = TT - 1;
            *(bfrag*)&Ks[row * LP + scol] =
                *(const bfrag*)(kbase + (size_t)tok * EE + scol);
            *(bfrag*)&Vt[row * LP + scol] =
                *(const bfrag*)(vbase + (size_t)row * TTP + k0 + scol);
        }
        __syncthreads();

        // S = Q K^T
        ffrag sv[4];
        #pragma unroll
        for (int j = 0; j < 4; j++) {
            bfrag kf0 = *(const bfrag*)&Ks[(j * 16 + cl) * LP + (qd << 3)];
            bfrag kf1 = *(const bfrag*)&Ks[(j * 16 + cl) * LP + 32 + (qd << 3)];
            ffrag z = {0.f, 0.f, 0.f, 0.f};
            z = __builtin_amdgcn_mfma_f32_16x16x32_bf16(qf0, kf0, z, 0, 0, 0);
            z = __builtin_amdgcn_mfma_f32_16x16x32_bf16(qf1, kf1, z, 0, 0, 0);
            sv[j] = z;
        }

        // mask (LOCAL masked out); scale folded into exp2
        #pragma unroll
        for (int j = 0; j < 4; j++) {
            #pragma unroll
            for (int r = 0; r < 4; r++) {
                bool masked = (kr[j] > 27) ||
                              (abs(qr_[r] - kr[j]) <= 4 && abs(qc_[r] - kc[j]) <= 4);
                if (masked) sv[j][r] = -3.0e38f;
            }
        }

        // online softmax (rows live in 16-lane groups sharing qd)
        #pragma unroll
        for (int r = 0; r < 4; r++) {
            float mx = fmaxf(fmaxf(sv[0][r], sv[1][r]), fmaxf(sv[2][r], sv[3][r]));
            mx = fmaxf(mx, __shfl_xor(mx, 1, 64));
            mx = fmaxf(mx, __shfl_xor(mx, 2, 64));
            mx = fmaxf(mx, __shfl_xor(mx, 4, 64));
            mx = fmaxf(mx, __shfl_xor(mx, 8, 64));
            float m_new = fmaxf(m_run[r], mx);
            float alpha = exp2f((m_run[r] - m_new) * SCL2);
            float p0 = exp2f((sv[0][r] - m_new) * SCL2);
            float p1 = exp2f((sv[1][r] - m_new) * SCL2);
            float p2 = exp2f((sv[2][r] - m_new) * SCL2);
            float p3 = exp2f((sv[3][r] - m_new) * SCL2);
            float rs = (p0 + p1) + (p2 + p3);
            rs += __shfl_xor(rs, 1, 64);
            rs += __shfl_xor(rs, 2, 64);
            rs += __shfl_xor(rs, 4, 64);
            rs += __shfl_xor(rs, 8, 64);
            l_run[r] = l_run[r] * alpha + rs;
            m_run[r] = m_new;
            #pragma unroll
            for (int t = 0; t < 4; t++) o_acc[t][r] *= alpha;
            int prow = (wave * 16 + (qd << 2) + r) * LP;
            Pb[prow + 0 * 16 + cl] = f2b(p0);
            Pb[prow + 1 * 16 + cl] = f2b(p1);
            Pb[prow + 2 * 16 + cl] = f2b(p2);
            Pb[prow + 3 * 16 + cl] = f2b(p3);
        }
        // Pb rows are wave-private: drain this wave's LDS writes only
        asm volatile("s_waitcnt lgkmcnt(0)" ::: "memory");

        // O += P @ V
        bfrag pf0 = *(const bfrag*)&Pb[(wave * 16 + cl) * LP + (qd << 3)];
        bfrag pf1 = *(const bfrag*)&Pb[(wave * 16 + cl) * LP + 32 + (qd << 3)];
        #pragma unroll
        for (int t = 0; t < 4; t++) {
            bfrag vf0 = *(const bfrag*)&Vt[(t * 16 + cl) * LP + (qd << 3)];
            bfrag vf1 = *(const bfrag*)&Vt[(t * 16 + cl) * LP + 32 + (qd << 3)];
            o_acc[t] = __builtin_amdgcn_mfma_f32_16x16x32_bf16(pf0, vf0, o_acc[t], 0, 0, 0);
            o_acc[t] = __builtin_amdgcn_mfma_f32_16x16x32_bf16(pf1, vf1, o_acc[t], 0, 0, 0);
        }

        // advance kr/kc by 64 tokens (64 = 2*28 + 8)
        #pragma unroll
        for (int j = 0; j < 4; j++) {
            kc[j] += 8; kr[j] += 2;
            if (kc[j] >= GG) { kc[j] -= GG; kr[j] += 1; }
        }
    }

    #pragma unroll
    for (int r = 0; r < 4; r++) {
        if (qg_[r] < TT) {
            float inv = 1.0f / fmaxf(l_run[r], 1e-30f);
            #pragma unroll
            for (int t = 0; t < 4; t++)
                O[(size_t)(b * TT + qg_[r]) * EE + hh * 64 + t * 16 + cl] =
                    f2b(o_acc[t][r] * inv);
        }
    }
}

// ---------------------------------------------------------------- head
__global__ __launch_bounds__(256) void head_kernel(const float* __restrict__ Y,
                                                   const float* __restrict__ hw,
                                                   const float* __restrict__ hb,
                                                   const float* __restrict__ mean_,
                                                   const float* __restrict__ std_,
                                                   float* __restrict__ out) {
    __shared__ float sb[4];
    int row = blockIdx.x;
    int tid = threadIdx.x;
    const float* y = Y + (size_t)row * EE;
    float v = y[tid] * hw[tid] + y[tid + 256] * hw[tid + 256] + y[tid + 512] * hw[tid + 512];
    v = block_reduce_sum256(v, sb);
    if (tid == 0) {
        float logit = v + hb[0];
        float z = logit * std_[0] + mean_[0];
        float f = expf(z * 2.302585092994046f) - 1e-8f;
        f = fminf(fmaxf(f, 1e-15f), 1.0f);
        out[4 + row] = f;
    }
}

__global__ __launch_bounds__(256) void flux_sum_kernel(float* __restrict__ out) {
    __shared__ float sb[4];
    int b = blockIdx.x;
    int tid = threadIdx.x;
    const float* pf = out + 4 + (size_t)b * TT;
    float v = pf[tid] + pf[tid + 256] + pf[tid + 512];
    if (tid < TT - 768) v += pf[tid + 768];
    v = block_reduce_sum256(v, sb);
    if (tid == 0) out[b] = fmaxf(v, 1e-15f);
}

// ---------------------------------------------------------------- host
extern "C" void kernel_launch(void* const* d_in, const int* in_sizes, int n_in,
                              void* d_out, int out_size, void* d_ws, size_t ws_size,
                              hipStream_t stream) {
    const float* x        = (const float*)d_in[0];
    const float* sxr_mean = (const float*)d_in[1];
    const float* sxr_std  = (const float*)d_in[2];
    const float* input_w  = (const float*)d_in[3];
    const float* input_b  = (const float*)d_in[4];
    const float* pos_emb  = (const float*)d_in[5];
    const float* ln1_w    = (const float*)d_in[6];
    const float* ln1_b    = (const float*)d_in[7];
    const float* in_w     = (const float*)d_in[8];
    const float* in_b     = (const float*)d_in[9];
    const float* out_w    = (const float*)d_in[10];
    const float* out_b    = (const float*)d_in[11];
    const float* ln2_w    = (const float*)d_in[12];
    const float* ln2_b    = (const float*)d_in[13];
    const float* w1       = (const float*)d_in[14];
    const float* b1       = (const float*)d_in[15];
    const float* w2       = (const float*)d_in[16];
    const float* b2       = (const float*)d_in[17];
    const float* head_ln_w = (const float*)d_in[18];
    const float* head_ln_b = (const float*)d_in[19];
    const float* head_w   = (const float*)d_in[20];
    const float* head_b   = (const float*)d_in[21];
    float* out = (float*)d_out;

    const size_t NROW = (size_t)BB * TT;               // 3136
    const size_t NE   = NROW * EE;

    float* h   = (float*)d_ws;                         // [3136,768] f32
    float* y32 = h + NE;                               // [3136,768] f32 (head only)
    unsigned short* q_b   = (unsigned short*)(y32 + NE);   // [3136,768] bf16
    unsigned short* k_b   = q_b + NE;                      // [3136,768] bf16
    unsigned short* vT_b  = k_b + NE;                      // [48*64, 832] bf16
    unsigned short* y_b   = vT_b + (size_t)BB * NHEAD * 64 * TTP;
    unsigned short* o_b   = y_b + NE;
    unsigned short* mlp_b = o_b + NE;                  // [3136,3072] bf16
    unsigned short* wq_b  = mlp_b + NROW * HDIM;
    unsigned short* wo_b  = wq_b + (size_t)3 * EE * EE;
    unsigned short* w1_b  = wo_b + (size_t)EE * EE;
    unsigned short* w2_b  = w1_b + (size_t)HDIM * EE;

    const int tot = BB * TT * EE;
    const int GY = (int)((NROW + 127) / 128);          // 25

    patchify_kernel<<<(tot + 255) / 256, 256, 0, stream>>>(x, mlp_b);
    cast_kernel<<<(EE * EE / 4 + 255) / 256, 256, 0, stream>>>(input_w, wo_b, EE * EE / 4);
    posfill_kernel<<<(tot + 255) / 256, 256, 0, stream>>>(h, pos_emb);
    gemm_bf16_sk<<<dim3(EE / 128, GY, 2), 256, 0, stream>>>(
        mlp_b, wo_b, input_b, h, (int)NROW, EE, EE, 384);

    for (int l = 0; l < NLAYER; l++) {
        fused_cast_kernel<<<6912, 256, 0, stream>>>(
            in_w + (size_t)l * 3 * EE * EE, out_w + (size_t)l * EE * EE,
            w1 + (size_t)l * HDIM * EE, w2 + (size_t)l * EE * HDIM,
            wq_b, wo_b, w1_b, w2_b);

        ln_kernel<<<(int)NROW, 256, 0, stream>>>(h, ln1_w + l * EE, ln1_b + l * EE, y_b, nullptr);
        gemm_qkv<<<dim3(3 * EE / 128, GY), 256, 0, stream>>>(
            y_b, wq_b, in_b + (size_t)l * 3 * EE, q_b, k_b, vT_b,
            (int)NROW, 3 * EE, EE);
        attn_kernel<<<dim3(13, BB * NHEAD), 256, 0, stream>>>(q_b, k_b, vT_b, o_b);
        gemm_bf16_sk<<<dim3(EE / 128, GY, 2), 256, 0, stream>>>(
            o_b, wo_b, out_b + (size_t)l * EE, h, (int)NROW, EE, EE, 384);
        ln_kernel<<<(int)NROW, 256, 0, stream>>>(h, ln2_w + l * EE, ln2_b + l * EE, y_b, nullptr);
        gemm_bf16<<<dim3(HDIM / 128, GY), 256, 0, stream>>>(
            y_b, w1_b, b1 + (size_t)l * HDIM, nullptr, nullptr, mlp_b,
            (int)NROW, HDIM, EE, 1);
        gemm_bf16_sk<<<dim3(EE / 128, GY, 4), 256, 0, stream>>>(
            mlp_b, w2_b, b2 + (size_t)l * EE, h, (int)NROW, EE, HDIM, 768);
    }

    ln_kernel<<<(int)NROW, 256, 0, stream>>>(h, head_ln_w, head_ln_b, y_b, y32);
    head_kernel<<<(int)NROW, 256, 0, stream>>>(y32, head_w, head_b, sxr_mean, sxr_std, out);
    flux_sum_kernel<<<BB, 256, 0, stream>>>(out);
}